// Round 8
// baseline (4222.990 us; speedup 1.0000x reference)
//
#include <hip/hip_runtime.h>

#define B_  4
#define S_  2048
#define D_  768
#define NH_ 4
#define DH_ 192

typedef short  s8v __attribute__((ext_vector_type(8)));
typedef float  f4v __attribute__((ext_vector_type(4)));
typedef unsigned short ushort_t;

static __device__ __forceinline__ ushort_t f2bf(float f) {
    union { float f; unsigned u; } v; v.f = f;
    unsigned r = v.u + 0x7fffu + ((v.u >> 16) & 1u);
    return (ushort_t)(r >> 16);
}
static __device__ __forceinline__ float bf2f(ushort_t b) {
    union { unsigned u; float f; } v; v.u = ((unsigned)b) << 16;
    return v.f;
}
static __device__ __forceinline__ f4v mfma16(s8v a, s8v b, f4v c) {
    return __builtin_amdgcn_mfma_f32_16x16x32_bf16(a, b, c, 0, 0, 0);
}

// ---------------------------------------------------------------------------
// Kernel 1: causal depthwise conv1d + swish -> x_conv (bf16); also x -> bf16.
// ---------------------------------------------------------------------------
__global__ void conv_kernel(const float* __restrict__ x, const float* __restrict__ ck,
                            const float* __restrict__ cb,
                            ushort_t* __restrict__ xconv, ushort_t* __restrict__ xb) {
    int idx = blockIdx.x * blockDim.x + threadIdx.x;   // over B*S*D/4
    const int nd4 = D_ / 4;
    int d4 = idx % nd4;
    int bs = idx / nd4;
    int s = bs % S_;
    int b = bs / S_;
    int d = d4 * 4;

    float4 acc = *(const float4*)(cb + d);
    float4 xcur = make_float4(0.f, 0.f, 0.f, 0.f);
#pragma unroll
    for (int k = 0; k < 4; ++k) {
        int sk = s - 3 + k;
        float4 xv = make_float4(0.f, 0.f, 0.f, 0.f);
        if (sk >= 0) xv = *(const float4*)(x + ((size_t)(b * S_ + sk) * D_ + d));
        if (k == 3) xcur = xv;
        float4 kv = *(const float4*)(ck + (size_t)k * D_ + d);
        acc.x += xv.x * kv.x; acc.y += xv.y * kv.y;
        acc.z += xv.z * kv.z; acc.w += xv.w * kv.w;
    }
    float c0 = acc.x / (1.f + __expf(-acc.x));
    float c1 = acc.y / (1.f + __expf(-acc.y));
    float c2 = acc.z / (1.f + __expf(-acc.z));
    float c3 = acc.w / (1.f + __expf(-acc.w));

    size_t base = (size_t)bs * D_ + d;
    ushort4 pc; pc.x = f2bf(c0); pc.y = f2bf(c1); pc.z = f2bf(c2); pc.w = f2bf(c3);
    *(ushort4*)(xconv + base) = pc;
    ushort4 px; px.x = f2bf(xcur.x); px.y = f2bf(xcur.y); px.z = f2bf(xcur.z); px.w = f2bf(xcur.w);
    *(ushort4*)(xb + base) = px;
}

// ---------------------------------------------------------------------------
// Kernel 2: gate pre-activation GEMMs (unchanged).
// G layout: [s][h][b][e][g] bf16, cell_bias folded in.
// ---------------------------------------------------------------------------
__launch_bounds__(768)
__global__ void gates_kernel(const ushort_t* __restrict__ xconv, const ushort_t* __restrict__ xb,
                             const float* __restrict__ Wi, const float* __restrict__ Wf,
                             const float* __restrict__ Wz, const float* __restrict__ Wo,
                             const float* __restrict__ cbias, ushort_t* __restrict__ G) {
    int sb = blockIdx.x, h = blockIdx.y, p = blockIdx.z;
    const ushort_t* X = (p == 0) ? xconv : xb;
    const float* W0 = (p == 0) ? Wi : Wz;
    const float* W1 = (p == 0) ? Wf : Wo;

    int tid = threadIdx.x;
    int lane = tid & 63;
    int w = tid >> 6;

    int col = w * 16 + (lane & 15);
    int kq0 = (lane >> 4) * 8;

    s8v B0[6], B1[6];
#pragma unroll
    for (int kt = 0; kt < 6; ++kt) {
        const float* w0p = W0 + ((size_t)(h * DH_ + kt * 32 + kq0)) * DH_ + col;
        const float* w1p = W1 + ((size_t)(h * DH_ + kt * 32 + kq0)) * DH_ + col;
        s8v f0, f1;
#pragma unroll
        for (int j = 0; j < 8; ++j) {
            f0[j] = (short)f2bf(w0p[(size_t)j * DH_]);
            f1[j] = (short)f2bf(w1p[(size_t)j * DH_]);
        }
        B0[kt] = f0; B1[kt] = f1;
    }
    float bias0 = cbias[(size_t)(2 * p) * D_ + h * DH_ + col];
    float bias1 = cbias[(size_t)(2 * p + 1) * D_ + h * DH_ + col];

    int b_l = lane & 3;
    int ds_l = (lane >> 2) & 3;

    for (int mt = 0; mt < 16; ++mt) {
        int s = sb * 64 + mt * 4 + ds_l;
        const ushort_t* ap = X + ((size_t)(b_l * S_ + s) * D_ + h * DH_ + kq0);
        s8v A[6];
#pragma unroll
        for (int kt = 0; kt < 6; ++kt) A[kt] = *(const s8v*)(ap + kt * 32);
        f4v a0 = {0.f, 0.f, 0.f, 0.f}, a1 = {0.f, 0.f, 0.f, 0.f};
#pragma unroll
        for (int kt = 0; kt < 6; ++kt) {
            a0 = mfma16(A[kt], B0[kt], a0);
            a1 = mfma16(A[kt], B1[kt], a1);
        }
        int sro = sb * 64 + mt * 4 + (lane >> 4);
#pragma unroll
        for (int r = 0; r < 4; ++r) {
            size_t idx = (((size_t)(sro * NH_ + h) * B_ + r) * DH_ + col) * 4;
            ushort2 pr;
            pr.x = f2bf(a0[r] + bias0);
            pr.y = f2bf(a1[r] + bias1);
            *(ushort2*)(G + idx + 2 * p) = pr;
        }
    }
}

// ---------------------------------------------------------------------------
// Kernel 2.5: zero xbuf ring slot 0 (tags=0 == step 0, payload=0 == h0), all
// heads. Runs after gates_kernel (input xb aliases this region).
// ---------------------------------------------------------------------------
__global__ void zero_kernel(unsigned* __restrict__ z) {
    for (int i = threadIdx.x; i < 3072; i += 256) z[i] = 0;
}

// ---------------------------------------------------------------------------
// Kernel 3: recurrence split 2 CUs per head (e-halves of 96). Grid = 16:
// block h = half 0 of head h, block h+8 = half 1. 12 waves = 6 e-tiles x
// 2 k-halves. kh0 waves: own-half h from LDS. kh1 waves: partner-half h via
// self-synchronizing tagged dwords ((step<<16)|bf16) in a PER-HEAD ring
// buffer (8 slots; pair skew <= 2 steps by construction; absolute tags
// disambiguate laps; poison tag 0xAAAA never matches a step).
// *** r5-r7 bug: xbuf lacked the head dimension -> all 4 heads clobbered the
// same exchange slots; tags (same value from every head) still matched. ***
// xbuf dword layout: slot(8) x head(4) x half(2) x b(4) x e_local(96).
// Partial C-frags reduced via LDS psum, then in-register gating
// (batch-replicated M rows, HW-verified in rounds 2-3).
// ---------------------------------------------------------------------------
__launch_bounds__(768)
__global__ void recur_kernel(const ushort_t* __restrict__ G, const float* __restrict__ Rw,
                             ushort_t* __restrict__ ys, unsigned* __restrict__ xbuf) {
    const int bid = blockIdx.x;
    const int head = bid & 7;
    if (head >= NH_) return;
    const int half = bid >> 3;

    const int tid = threadIdx.x;
    const int lane = tid & 63;
    const int wv = tid >> 6;
    const int et = wv >> 1;        // 0..5 : local e-tile
    const int kh = wv & 1;         // 0 = own-k (LDS), 1 = partner-k (xbuf)
    const int c = lane & 15;
    const int t = lane >> 4;       // A k-quad / C batch row

    __shared__ ushort_t h_lds[2][4][104];   // [buf][b][klocal 0..95 +pad]
    __shared__ f4v psum[6][64];             // kh1 partial C-frags

    const int e_col = half * 96 + et * 16 + c;          // head-local e
    const int k_src = (kh == 0) ? half * 96 : (1 - half) * 96;

    // B fragments: R[k = k_src + ktl*32 + t*8 + j][e_col], 4 gates x 3 kt
    s8v Bf[4][3];
#pragma unroll
    for (int g = 0; g < 4; ++g)
#pragma unroll
        for (int ktl = 0; ktl < 3; ++ktl) {
            const float* rp = Rw + ((size_t)((g * NH_ + head) * DH_ + k_src + ktl * 32 + t * 8)) * DH_ + e_col;
            s8v f;
#pragma unroll
            for (int j = 0; j < 8; ++j) f[j] = (short)f2bf(rp[(size_t)j * DH_]);
            Bf[g][ktl] = f;
        }

    for (int i = tid; i < 2 * 4 * 104; i += 768) (&h_lds[0][0][0])[i] = 0;

    const int b_id = t;
    const int e_loc = et * 16 + c;

    float m_st = 0.f, c_st = 0.f, n_st = 0.f;
    const float LOG2E = 1.44269504088896f;

    // per-head exchange ring: slot*3072 + head*768 + half*384 + b*96 + e
    unsigned* const xw = xbuf + (size_t)head * 768 + (size_t)half * 384 + b_id * 96 + e_loc;
    const unsigned* const xr = xbuf + (size_t)head * 768 + (size_t)(1 - half) * 384
                                    + (c >> 2) * 96 + t * 8;

    const int gstride = NH_ * B_ * DH_ * 4;
    const ushort_t* gp = G + (((size_t)head * B_ + b_id) * DH_ + e_col) * 4;
    ushort4 gv_n = make_ushort4(0, 0, 0, 0);
    if (kh == 0) gv_n = *(const ushort4*)gp;

    ushort_t* yp = ys + ((size_t)head * B_ + b_id) * DH_ + e_col;

    __syncthreads();

    for (int s = 0; s < S_; ++s) {
        const int p = s & 1;
        ushort4 gv = make_ushort4(0, 0, 0, 0);
        s8v A[3];

        if (kh == 0) {
            gv = gv_n;
            if (s + 1 < S_) gp += gstride;
            gv_n = *(const ushort4*)gp;                     // prefetch next step
            const ushort_t* ab = &h_lds[p][c >> 2][t * 8];
#pragma unroll
            for (int ktl = 0; ktl < 3; ++ktl)
                A[ktl] = *(const s8v*)(ab + ktl * 32);
        } else {
            // spin until every dword of the fragment carries this step's tag
            const unsigned* rb = xr + (size_t)(s & 7) * 3072;
            unsigned dw[3][8];
            for (;;) {
                bool ok = true;
#pragma unroll
                for (int ktl = 0; ktl < 3; ++ktl)
#pragma unroll
                    for (int j = 0; j < 8; ++j) {
                        dw[ktl][j] = __hip_atomic_load(rb + ktl * 32 + j,
                                         __ATOMIC_RELAXED, __HIP_MEMORY_SCOPE_SYSTEM);
                        ok = ok && ((int)(dw[ktl][j] >> 16) == s);
                    }
                if (ok) break;
            }
#pragma unroll
            for (int ktl = 0; ktl < 3; ++ktl) {
                s8v a;
#pragma unroll
                for (int j = 0; j < 8; ++j) a[j] = (short)(dw[ktl][j] & 0xffffu);
                A[ktl] = a;
            }
        }

        f4v acc[4];
#pragma unroll
        for (int g = 0; g < 4; ++g) { acc[g][0] = 0.f; acc[g][1] = 0.f; acc[g][2] = 0.f; acc[g][3] = 0.f; }
#pragma unroll
        for (int ktl = 0; ktl < 3; ++ktl)
#pragma unroll
            for (int g = 0; g < 4; ++g)
                acc[g] = mfma16(A[ktl], Bf[g][ktl], acc[g]);

        if (kh == 1) {
            f4v v; v[0] = acc[0][0]; v[1] = acc[1][0]; v[2] = acc[2][0]; v[3] = acc[3][0];
            psum[et][lane] = v;
        }
        asm volatile("s_waitcnt lgkmcnt(0)\n\ts_barrier" ::: "memory");   // psum ready

        if (kh == 0) {
            f4v rd = psum[et][lane];
            float it = acc[0][0] + rd[0] + bf2f(gv.x);
            float ft = acc[1][0] + rd[1] + bf2f(gv.y);
            float zt = acc[2][0] + rd[2] + bf2f(gv.z);
            float ot = acc[3][0] + rd[3] + bf2f(gv.w);

            float fm = ft + m_st;
            float mn = fmaxf(fm, it);
            float ia = __builtin_amdgcn_exp2f((it - mn) * LOG2E);
            float fa = __builtin_amdgcn_exp2f((fm - mn) * LOG2E);
            float ez = __builtin_amdgcn_exp2f(zt * (2.f * LOG2E));
            float th = 1.f - 2.f * __builtin_amdgcn_rcpf(ez + 1.f);
            float cn = fa * c_st + ia * th;
            float nn = fa * n_st + ia;
            float sg = __builtin_amdgcn_rcpf(1.f + __builtin_amdgcn_exp2f(-ot * LOG2E));
            float hn = sg * cn * __builtin_amdgcn_rcpf(nn);
            m_st = mn; c_st = cn; n_st = nn;

            ushort_t hb = f2bf(hn);
            h_lds[1 - p][b_id][e_loc] = hb;

            // publish own value for step s+1 into ring slot (s+1)&7, tagged
            __hip_atomic_store(xw + (size_t)((s + 1) & 7) * 3072,
                               ((unsigned)(s + 1) << 16) | (unsigned)hb,
                               __ATOMIC_RELAXED, __HIP_MEMORY_SCOPE_SYSTEM);
            *yp = hb;
            yp += NH_ * B_ * DH_;
        }

        // lgkm-only: orders the h_lds ping-pong; global stores need no ordering
        asm volatile("s_waitcnt lgkmcnt(0)\n\ts_barrier" ::: "memory");
    }
}

// ---------------------------------------------------------------------------
// Kernel 4: multi-head layernorm. One wave per (b,s,h) group of 192.
// ---------------------------------------------------------------------------
__global__ void ln_kernel(const ushort_t* __restrict__ ys, const float* __restrict__ gn,
                          float* __restrict__ out) {
    int gw = (blockIdx.x * blockDim.x + threadIdx.x) >> 6;   // 0 .. 32767
    int lane = threadIdx.x & 63;
    int b = gw & 3;
    int h = (gw >> 2) & 3;
    int s = gw >> 4;

    const ushort_t* yp = ys + (size_t)gw * DH_;
    float v0 = bf2f(yp[lane]);
    float v1 = bf2f(yp[lane + 64]);
    float v2 = bf2f(yp[lane + 128]);
    float sum = v0 + v1 + v2;
    float sq  = v0 * v0 + v1 * v1 + v2 * v2;
#pragma unroll
    for (int off = 32; off > 0; off >>= 1) {
        sum += __shfl_xor(sum, off, 64);
        sq  += __shfl_xor(sq,  off, 64);
    }
    float mu  = sum * (1.f / 192.f);
    float var = sq * (1.f / 192.f) - mu * mu;
    float rs  = rsqrtf(var + 1e-5f);

    float* op = out + (size_t)(b * S_ + s) * D_ + h * DH_;
    const float* gp = gn + h * DH_;
    op[lane]       = (v0 - mu) * rs * gp[lane];
    op[lane + 64]  = (v1 - mu) * rs * gp[lane + 64];
    op[lane + 128] = (v2 - mu) * rs * gp[lane + 128];
}

// ---------------------------------------------------------------------------
// Workspace plan (75.5 MB total, < the 88 MB rounds 1-3 proved available):
//   [0, nBSD)        xconv (conv->gates)  ... then reused as ys (recur->ln)
//   [nBSD, 2*nBSD)   xb    (conv->gates)  ... then reused as xbuf ring (98 KB)
//   [2*nBSD, ...)    G     (gates->recur)
// Reuse is safe: kernels are stream-ordered; second users run strictly after
// first users' last read.
// ---------------------------------------------------------------------------
extern "C" void kernel_launch(void* const* d_in, const int* in_sizes, int n_in,
                              void* d_out, int out_size, void* d_ws, size_t ws_size,
                              hipStream_t stream) {
    const float* x     = (const float*)d_in[0];
    const float* ck    = (const float*)d_in[1];
    const float* cb    = (const float*)d_in[2];
    const float* Wi    = (const float*)d_in[3];
    const float* Wf    = (const float*)d_in[4];
    const float* Wz    = (const float*)d_in[5];
    const float* Wo    = (const float*)d_in[6];
    const float* Rw    = (const float*)d_in[7];
    const float* cbias = (const float*)d_in[8];
    const float* gn    = (const float*)d_in[9];
    float* out = (float*)d_out;

    const size_t nBSD = (size_t)B_ * S_ * D_;              // 6291456
    ushort_t* xconv = (ushort_t*)d_ws;
    ushort_t* xb    = xconv + nBSD;
    ushort_t* G     = xb + nBSD;                           // S*NH*B*DH*4
    ushort_t* ys    = xconv;                               // alias: xconv dead after gates
    unsigned* xbuf  = (unsigned*)xb;                       // alias: xb dead after gates

    conv_kernel<<<dim3(B_ * S_ * D_ / 4 / 256), dim3(256), 0, stream>>>(x, ck, cb, xconv, xb);
    gates_kernel<<<dim3(32, NH_, 2), dim3(768), 0, stream>>>(xconv, xb, Wi, Wf, Wz, Wo, cbias, G);
    zero_kernel<<<dim3(1), dim3(256), 0, stream>>>(xbuf);
    recur_kernel<<<dim3(16), dim3(768), 0, stream>>>(G, Rw, ys, xbuf);
    ln_kernel<<<dim3(8192), dim3(256), 0, stream>>>(ys, gn, out);
}